// Round 8
// baseline (460.837 us; speedup 1.0000x reference)
//
#include <hip/hip_runtime.h>

#define TT 512
#define BIGS 1.4426950408889634e10f   // BIG(1e10) * log2(e), scaled domain
#define LOG2E 1.4426950408889634f
#define M2L  (-2.0f * 1.4426950408889634f)
#define LN2F 0.69314718055994531f

typedef _Float16 h2 __attribute__((ext_vector_type(2)));

__device__ __forceinline__ unsigned pk(float a, float b) {
    h2 v; v.x = (_Float16)a; v.y = (_Float16)b;
    return __builtin_bit_cast(unsigned, v);
}

#if __has_builtin(__builtin_amdgcn_fdot2)
#define FDOT2(a, b, c) __builtin_amdgcn_fdot2(__builtin_bit_cast(h2, (a)), \
                                              __builtin_bit_cast(h2, (b)), (c), false)
#else
__device__ __forceinline__ float fdot2_sw(unsigned a, unsigned b, float c) {
    h2 ha = __builtin_bit_cast(h2, a), hb = __builtin_bit_cast(h2, b);
    return c + (float)ha.x * (float)hb.x + (float)ha.y * (float)hb.y;
}
#define FDOT2(a, b, c) fdot2_sw((a), (b), (c))
#endif

// ---------------------------------------------------------------------------
// Column-marching lane-skewed SoftDTW. One wave per sample. Lane t owns rows
// 8t..8t+7 (X in registers); at tick tau it processes the vertical 8-cell
// strip of column j = tau - t. Cross-lane dependency: one __shfl_up per tick
// (lane t-1's bottom-row value at column j; the column j-1 copy is last
// tick's shfl, kept in u_old). In-lane vertical chain handled sequentially
// within the tick. 576 ticks total (vs 1023 diagonals at 50% cell-slot
// utilization for diagonal marching). Z row for the NEXT tick prefetched
// into a ping-pong register buffer from a bit-permuted LDS image. Borders
// are exact with no masking: Rp init BIGS, u_old init (t==0 ? 0 : BIGS) and
// exp2(x - BIGS) == 0 makes softmin degrade exactly to the valid terms.
// Base-2 scaled domain (values = true * log2(e)).
// ---------------------------------------------------------------------------
__global__ __launch_bounds__(64, 1) void k_fused(const float* __restrict__ X,
                                                 const float* __restrict__ Z,
                                                 const float* __restrict__ w,
                                                 float* __restrict__ out) {
    const int n = blockIdx.x;
    const int t = threadIdx.x;

    __shared__ uint4 ZA[2][512];     // [half][permuted idx] 16 KiB
    __shared__ float Zs2p[512];      // LOG2E*|z|^2 at permuted idx

    // ---- stage Z into LDS (lane t handles rows 8t..8t+7) ----
#pragma unroll
    for (int k2 = 0; k2 < 8; ++k2) {
        const int r = 8 * t + k2;
        const float4* zp = (const float4*)(Z + (size_t)r * 16);
        const float4 a0 = zp[0], a1 = zp[1], a2 = zp[2], a3 = zp[3];
        float sv = 0.0f;
        sv = fmaf(a0.x, a0.x, sv); sv = fmaf(a0.y, a0.y, sv);
        sv = fmaf(a0.z, a0.z, sv); sv = fmaf(a0.w, a0.w, sv);
        sv = fmaf(a1.x, a1.x, sv); sv = fmaf(a1.y, a1.y, sv);
        sv = fmaf(a1.z, a1.z, sv); sv = fmaf(a1.w, a1.w, sv);
        sv = fmaf(a2.x, a2.x, sv); sv = fmaf(a2.y, a2.y, sv);
        sv = fmaf(a2.z, a2.z, sv); sv = fmaf(a2.w, a2.w, sv);
        sv = fmaf(a3.x, a3.x, sv); sv = fmaf(a3.y, a3.y, sv);
        sv = fmaf(a3.z, a3.z, sv); sv = fmaf(a3.w, a3.w, sv);
        const int idx = ((r & 1) << 8) | (r >> 1);
        ZA[0][idx] = make_uint4(pk(a0.x, a0.y), pk(a0.z, a0.w),
                                pk(a1.x, a1.y), pk(a1.z, a1.w));
        ZA[1][idx] = make_uint4(pk(a2.x, a2.y), pk(a2.z, a2.w),
                                pk(a3.x, a3.y), pk(a3.z, a3.w));
        Zs2p[idx] = LOG2E * sv;
    }

    // ---- X rows for this lane -> registers ----
    unsigned Xu[8][8];
    float    xs2[8];
    const float* xp = X + ((size_t)n * TT + 8 * t) * 16;
#pragma unroll
    for (int q = 0; q < 8; ++q) {
        const float4* xr = (const float4*)(xp + q * 16);
        const float4 a0 = xr[0], a1 = xr[1], a2 = xr[2], a3 = xr[3];
        float sv = 0.0f;
        sv = fmaf(a0.x, a0.x, sv); sv = fmaf(a0.y, a0.y, sv);
        sv = fmaf(a0.z, a0.z, sv); sv = fmaf(a0.w, a0.w, sv);
        sv = fmaf(a1.x, a1.x, sv); sv = fmaf(a1.y, a1.y, sv);
        sv = fmaf(a1.z, a1.z, sv); sv = fmaf(a1.w, a1.w, sv);
        sv = fmaf(a2.x, a2.x, sv); sv = fmaf(a2.y, a2.y, sv);
        sv = fmaf(a2.z, a2.z, sv); sv = fmaf(a2.w, a2.w, sv);
        sv = fmaf(a3.x, a3.x, sv); sv = fmaf(a3.y, a3.y, sv);
        sv = fmaf(a3.z, a3.z, sv); sv = fmaf(a3.w, a3.w, sv);
        xs2[q] = LOG2E * sv;
        Xu[q][0] = pk(a0.x, a0.y); Xu[q][1] = pk(a0.z, a0.w);
        Xu[q][2] = pk(a1.x, a1.y); Xu[q][3] = pk(a1.z, a1.w);
        Xu[q][4] = pk(a2.x, a2.y); Xu[q][5] = pk(a2.z, a2.w);
        Xu[q][6] = pk(a3.x, a3.y); Xu[q][7] = pk(a3.z, a3.w);
    }
    const float wgt = w[n];
    __syncthreads();

    float Rp[8];                     // R[row 8t+q][previous column]
#pragma unroll
    for (int q = 0; q < 8; ++q) Rp[q] = BIGS;
    float u_old = (t == 0) ? 0.0f : BIGS;   // R[8t-1][j-1]; lane0 tick0 = corner 0

    uint4 Zb[2][2];                  // ping-pong Z-row buffer (2 halves)
    float Ssb[2];                    // LOG2E*|z_row|^2 for the buffered row
    // prime buffer 0 for tick 0 (lane 0 needs row 0; others inactive)
    Zb[0][0] = ZA[0][0]; Zb[0][1] = ZA[1][0]; Ssb[0] = Zs2p[0];
    Zb[1][0] = Zb[0][0]; Zb[1][1] = Zb[0][1]; Ssb[1] = Ssb[0];

    // One tick: par = tv&1 selects the primed Z buffer.
#define TICK(par, tv)                                                          \
    {                                                                          \
        float u_new = __shfl_up(Rp[7], 1);                                     \
        if (t == 0) u_new = BIGS;                                              \
        /* prefetch Z row for tick tv+1 (j = tv+1-t, clamped) */               \
        {                                                                      \
            int jn = (tv) + 1 - t;                                             \
            jn = jn < 0 ? 0 : (jn > 511 ? 511 : jn);                           \
            const int xn = ((jn & 1) << 8) | (jn >> 1);                        \
            Zb[1 - (par)][0] = ZA[0][xn];                                      \
            Zb[1 - (par)][1] = ZA[1][xn];                                      \
            Ssb[1 - (par)] = Zs2p[xn];                                         \
        }                                                                      \
        const int j = (tv) - t;                                                \
        if (j >= 0 && j < 512) {                                               \
            const uint4 z0 = Zb[(par)][0], z1 = Zb[(par)][1];                  \
            const float xz = Ssb[(par)];                                       \
            float dd[8];                                                       \
            _Pragma("unroll")                                                  \
            for (int q = 0; q < 8; ++q) {                                      \
                float acc = 0.0f;                                              \
                acc = FDOT2(z0.x, Xu[q][0], acc);                              \
                acc = FDOT2(z0.y, Xu[q][1], acc);                              \
                acc = FDOT2(z0.z, Xu[q][2], acc);                              \
                acc = FDOT2(z0.w, Xu[q][3], acc);                              \
                acc = FDOT2(z1.x, Xu[q][4], acc);                              \
                acc = FDOT2(z1.y, Xu[q][5], acc);                              \
                acc = FDOT2(z1.z, Xu[q][6], acc);                              \
                acc = FDOT2(z1.w, Xu[q][7], acc);                              \
                dd[q] = fmaf(M2L, acc, xs2[q] + xz);                           \
            }                                                                  \
            float up = u_new, pd = u_old;                                      \
            _Pragma("unroll")                                                  \
            for (int q = 0; q < 8; ++q) {                                      \
                const float pl = Rp[q];                                        \
                const float mn = fminf(fminf(up, pl), pd);                     \
                const float md = __builtin_amdgcn_fmed3f(up, pl, pd);          \
                const float mx = fmaxf(fmaxf(up, pl), pd);                     \
                const float sm = 1.0f + exp2f(mn - md) + exp2f(mn - mx);       \
                const float v = dd[q] + mn - log2f(sm);                        \
                pd = pl;            /* old R[i][j-1] = diag for row i+1 */     \
                Rp[q] = v;                                                     \
                up = v;             /* R[i][j] = up for row i+1 */             \
            }                                                                  \
        }                                                                      \
        u_old = u_new;                                                         \
    }

#pragma unroll 1
    for (int tau = 0; tau < 576; tau += 2) {
        TICK(0, tau)
        TICK(1, tau + 1)
    }
#undef TICK

    // lane 63 Rp[7] = R[511][511] (scaled); unscale and accumulate
    if (t == 63) atomicAdd(out, wgt * Rp[7] * LN2F);
}

__global__ void k_zero(float* out) {
    if (threadIdx.x == 0) out[0] = 0.0f;
}

extern "C" void kernel_launch(void* const* d_in, const int* in_sizes, int n_in,
                              void* d_out, int out_size, void* d_ws, size_t ws_size,
                              hipStream_t stream) {
    const float* X = (const float*)d_in[0];   // (64, 512, 16) f32
    const float* w = (const float*)d_in[1];   // (64,) f32
    const float* Z = (const float*)d_in[2];   // (512, 16) f32
    float* out = (float*)d_out;               // scalar f32

    hipLaunchKernelGGL(k_zero, dim3(1), dim3(64), 0, stream, out);
    hipLaunchKernelGGL(k_fused, dim3(64), dim3(64), 0, stream, X, Z, w, out);
}